// Round 7
// baseline (73.627 us; speedup 1.0000x reference)
//
#include <hip/hip_runtime.h>
#include <math.h>

// Problem constants (fixed by setup_inputs).
#define CC 4
#define NN 4096                  // vertices per class (== queries per class)
#define MM 4096
#define DD 32
#define GR 10                    // grid resolution per axis
#define NCELL (GR * GR * GR)     // 1000 cells per class
#define CAP 16                   // bucket capacity (P(Poisson(4.1)>16)~1e-6/cell)
#define LPQ 16                   // lanes cooperating per query
#define BBLK 256
#define QBLK 256

// ws layout (bytes):
//   cnt      u32[CC*NCELL]        @ 0        (16000)
//   spillCnt u32[CC]              @ 16000    (16)     <- memset covers [0,16016)
//   buckets  float4[CC*NCELL*CAP] @ 16384    (1024000)
//   spill    float4[CC*NN]        @ 1048576  (262144)
#define WS_ZERO_BYTES 16016
#define WS_SPILLCNT   16000
#define WS_BUCKETS    16384
#define WS_SPILL      (1 << 20)

__device__ __forceinline__ int cellof(float x) {
    int c = (int)(x * (float)GR);
    return min(max(c, 0), GR - 1);
}

// Branchless sorted-insert of (d, j) into top-3 (d0<=d1<=d2). Strict <
// keeps earlier entries on ties (matches jax top_k tie-break).
__device__ __forceinline__ void ins3b(float d, int j,
                                      float& d0, float& d1, float& d2,
                                      int& i0, int& i1, int& i2) {
    bool l2 = d < d2, l1 = d < d1, l0 = d < d0;
    d2 = l1 ? d1 : (l2 ? d : d2);
    i2 = l1 ? i1 : (l2 ? j : i2);
    d1 = l0 ? d0 : (l1 ? d : d1);
    i1 = l0 ? i0 : (l1 ? j : i1);
    d0 = l0 ? d : d0;
    i0 = l0 ? j : i0;
}

// One-phase, full-device-wide build: one thread per vertex. No scan, no
// block cooperation -> no serial per-CU critical path.
__global__ __launch_bounds__(BBLK) void k_build(
    const float* __restrict__ verts,      // [CC,NN,3]
    unsigned* __restrict__ cnt,           // [CC*NCELL]
    unsigned* __restrict__ spillCnt,      // [CC]
    float4* __restrict__ buckets,         // [CC*NCELL][CAP]
    float4* __restrict__ spill)           // [CC][NN]
{
    const int i = blockIdx.x * BBLK + threadIdx.x;   // 0..CC*NN-1
    const int c = i >> 12;
    const float x = verts[3 * i], y = verts[3 * i + 1], z = verts[3 * i + 2];
    const int cell = c * NCELL + (cellof(x) * GR + cellof(y)) * GR + cellof(z);
    const float4 p = make_float4(x, y, z, __int_as_float(i & (NN - 1)));
    const unsigned pos = atomicAdd(&cnt[cell], 1u);
    if (pos < CAP) {
        buckets[(size_t)cell * CAP + pos] = p;
    } else {                               // ~never (exactness fallback)
        const unsigned s = atomicAdd(&spillCnt[c], 1u);
        spill[(size_t)c * NN + s] = p;
    }
}

// 16 lanes per query, raw query order (predicated batch => data-independent
// cost, so divergence is harmless; output writes coalesce directly).
// Two dependent memory steps: 27 cell counts, then 27 count-clamped point
// loads. Spill list always folded in (zero-trip in practice). Exact via
// certificate + rare expanding rescan.
__global__ __launch_bounds__(QBLK, 4) void k_query(
    const float2* __restrict__ feat2,     // [CC*NN][16] float2
    const float* __restrict__ nverts,     // [CC*MM*3]
    const unsigned* __restrict__ cnt,     // [CC*NCELL]
    const unsigned* __restrict__ spillCnt,// [CC]
    const float4* __restrict__ buckets,   // [CC*NCELL][CAP]
    const float4* __restrict__ spill,     // [CC][NN]
    float2* __restrict__ out2)            // [CC*MM][16] float2
{
    const int tid  = threadIdx.x;
    const int t    = tid & (LPQ - 1);
    const int slot = (blockIdx.x * QBLK + tid) >> 4;   // 0..CC*MM-1
    const int c    = slot >> 12;

    const float qx = nverts[3 * slot + 0];
    const float qy = nverts[3 * slot + 1];
    const float qz = nverts[3 * slot + 2];

    const int cx = cellof(qx), cy = cellof(qy), cz = cellof(qz);
    const int offb = (c == 0) ? NN : (-c * NN);   // off-block 1.0 seed indices
    const float cs = 1.0f / (float)GR;
    const int cbase = c * NCELL;

    float d0 = 1.0f, d1 = 1.0f, d2 = 1.0f;
    int   i0 = offb, i1 = offb + 1, i2 = offb + 2;

    // ---- step 1: all 27 neighbor-cell counts (independent loads) ----
    unsigned cnts[27];
    int      cellid[27];
    #pragma unroll
    for (int k = 0; k < 27; ++k) {
        const int px = cx + k / 9 - 1;
        const int py = cy + (k / 3) % 3 - 1;
        const int pz = cz + k % 3 - 1;
        const bool ok = (px >= 0) & (px < GR) & (py >= 0) & (py < GR) &
                        (pz >= 0) & (pz < GR);
        const int cid = ok ? (cbase + (px * GR + py) * GR + pz) : cbase;
        cellid[k] = cid;
        const unsigned v = cnt[cid];
        cnts[k] = ok ? min(v, (unsigned)CAP) : 0u;
    }
    const unsigned sc = spillCnt[c];

    // ---- step 2: 27 point loads, lane address clamped by count ----
    #pragma unroll
    for (int b = 0; b < 3; ++b) {
        float4 P[9];
        #pragma unroll
        for (int j = 0; j < 9; ++j) {
            const int k = b * 9 + j;
            const unsigned ls = ((unsigned)t < cnts[k]) ? (unsigned)t : 0u;
            P[j] = buckets[(size_t)cellid[k] * CAP + ls];
        }
        #pragma unroll
        for (int j = 0; j < 9; ++j) {
            const int k = b * 9 + j;
            const float dx = P[j].x - qx, dy = P[j].y - qy, dz = P[j].z - qz;
            float dd = fmaf(dx, dx, fmaf(dy, dy, dz * dz));
            dd = ((unsigned)t < cnts[k]) ? dd : 1e30f;
            ins3b(dd, __float_as_int(P[j].w), d0, d1, d2, i0, i1, i2);
        }
    }
    // Spill points (lane-strided so each candidate lives in exactly one lane).
    for (unsigned s = (unsigned)t; s < sc; s += LPQ) {
        const float4 p = spill[(size_t)c * NN + s];
        const float dx = p.x - qx, dy = p.y - qy, dz = p.z - qz;
        const float dd = fmaf(dx, dx, fmaf(dy, dy, dz * dz));
        ins3b(dd, __float_as_int(p.w), d0, d1, d2, i0, i1, i2);
    }

    // Merge sorted triples across the 16-lane group.
    #pragma unroll
    for (int mask = 1; mask < LPQ; mask <<= 1) {
        const float e0 = __shfl_xor(d0, mask);
        const float e1 = __shfl_xor(d1, mask);
        const float e2 = __shfl_xor(d2, mask);
        const int   j0 = __shfl_xor(i0, mask);
        const int   j1 = __shfl_xor(i1, mask);
        const int   j2 = __shfl_xor(i2, mask);
        ins3b(e0, j0, d0, d1, d2, i0, i1, i2);
        ins3b(e1, j1, d0, d1, d2, i0, i1, i2);
        ins3b(e2, j2, d0, d1, d2, i0, i1, i2);
    }

    // Certificate for r=1 (group-uniform; rmin >= cs when interior).
    {
        const int lx = max(cx - 1, 0), hx = min(cx + 1, GR - 1);
        const int ly = max(cy - 1, 0), hy = min(cy + 1, GR - 1);
        const int lz = max(cz - 1, 0), hz = min(cz + 1, GR - 1);
        float rmin = 1e30f;
        if (lx > 0)      rmin = fminf(rmin, qx - (float)lx * cs);
        if (hx < GR - 1) rmin = fminf(rmin, (float)(hx + 1) * cs - qx);
        if (ly > 0)      rmin = fminf(rmin, qy - (float)ly * cs);
        if (hy < GR - 1) rmin = fminf(rmin, (float)(hy + 1) * cs - qy);
        if (lz > 0)      rmin = fminf(rmin, qz - (float)lz * cs);
        if (hz < GR - 1) rmin = fminf(rmin, (float)(hz + 1) * cs - qz);

        if (!(d2 <= rmin * rmin)) {
            // Rare (P ~ 5.8e-6/query): expanding exact rescan from seeds.
            for (int r = 2;; ++r) {
                d0 = d1 = d2 = 1.0f;
                i0 = offb; i1 = offb + 1; i2 = offb + 2;
                const int Lx = max(cx - r, 0), Hx = min(cx + r, GR - 1);
                const int Ly = max(cy - r, 0), Hy = min(cy + r, GR - 1);
                const int Lz = max(cz - r, 0), Hz = min(cz + r, GR - 1);
                for (int px = Lx; px <= Hx; ++px) {
                    for (int py = Ly; py <= Hy; ++py) {
                        for (int pz = Lz; pz <= Hz; ++pz) {
                            const int cid = cbase + (px * GR + py) * GR + pz;
                            const unsigned n = min(cnt[cid], (unsigned)CAP);
                            if ((unsigned)t < n) {
                                const float4 p =
                                    buckets[(size_t)cid * CAP + t];
                                const float dx = p.x - qx, dy = p.y - qy,
                                            dz = p.z - qz;
                                const float dd =
                                    fmaf(dx, dx, fmaf(dy, dy, dz * dz));
                                ins3b(dd, __float_as_int(p.w),
                                      d0, d1, d2, i0, i1, i2);
                            }
                        }
                    }
                }
                for (unsigned s = (unsigned)t; s < sc; s += LPQ) {
                    const float4 p = spill[(size_t)c * NN + s];
                    const float dx = p.x - qx, dy = p.y - qy, dz = p.z - qz;
                    const float dd = fmaf(dx, dx, fmaf(dy, dy, dz * dz));
                    ins3b(dd, __float_as_int(p.w), d0, d1, d2, i0, i1, i2);
                }
                #pragma unroll
                for (int mask = 1; mask < LPQ; mask <<= 1) {
                    const float e0 = __shfl_xor(d0, mask);
                    const float e1 = __shfl_xor(d1, mask);
                    const float e2 = __shfl_xor(d2, mask);
                    const int   j0 = __shfl_xor(i0, mask);
                    const int   j1 = __shfl_xor(i1, mask);
                    const int   j2 = __shfl_xor(i2, mask);
                    ins3b(e0, j0, d0, d1, d2, i0, i1, i2);
                    ins3b(e1, j1, d0, d1, d2, i0, i1, i2);
                    ins3b(e2, j2, d0, d1, d2, i0, i1, i2);
                }
                float rm = 1e30f;
                if (Lx > 0)      rm = fminf(rm, qx - (float)Lx * cs);
                if (Hx < GR - 1) rm = fminf(rm, (float)(Hx + 1) * cs - qx);
                if (Ly > 0)      rm = fminf(rm, qy - (float)Ly * cs);
                if (Hy < GR - 1) rm = fminf(rm, (float)(Hy + 1) * cs - qy);
                if (Lz > 0)      rm = fminf(rm, qz - (float)Lz * cs);
                if (Hz < GR - 1) rm = fminf(rm, (float)(Hz + 1) * cs - qz);
                const bool full = (Lx == 0 && Ly == 0 && Lz == 0 &&
                                   Hx == GR - 1 && Hy == GR - 1 &&
                                   Hz == GR - 1);
                if (full || d2 <= rm * rm) break;
            }
        }
    }

    // Fused epilogue: softmax(-d) + weighted feature gather (float2/lane).
    float w1 = expf(d0 - d1);
    float w2 = expf(d0 - d2);
    const float inv = 1.0f / (1.0f + w1 + w2);
    const float w0 = inv;
    w1 *= inv; w2 *= inv;

    const float2 a = feat2[(size_t)(i0 + c * NN) * 16 + t];
    const float2 b = feat2[(size_t)(i1 + c * NN) * 16 + t];
    const float2 g = feat2[(size_t)(i2 + c * NN) * 16 + t];
    float2 o;
    o.x = w0 * a.x + w1 * b.x + w2 * g.x;
    o.y = w0 * a.y + w1 * b.y + w2 * g.y;
    out2[(size_t)slot * 16 + t] = o;     // raw order -> fully coalesced
}

extern "C" void kernel_launch(void* const* d_in, const int* in_sizes, int n_in,
                              void* d_out, int out_size, void* d_ws, size_t ws_size,
                              hipStream_t stream) {
    const float* feat   = (const float*)d_in[0];   // points_feat [1, C*N, D] f32
    const float* verts  = (const float*)d_in[1];   // vertices    [C, N, 3]  f32
    const float* nverts = (const float*)d_in[2];   // new_vertices[C, M, 3]  f32
    float* outp = (float*)d_out;                   // [1, C*M, D] f32

    unsigned* cnt      = (unsigned*)d_ws;
    unsigned* spillCnt = (unsigned*)((char*)d_ws + WS_SPILLCNT);
    float4*   buckets  = (float4*)((char*)d_ws + WS_BUCKETS);
    float4*   spill    = (float4*)((char*)d_ws + WS_SPILL);

    hipMemsetAsync(d_ws, 0, WS_ZERO_BYTES, stream);
    k_build<<<dim3(CC * NN / BBLK), dim3(BBLK), 0, stream>>>(
        verts, cnt, spillCnt, buckets, spill);
    k_query<<<dim3(CC * MM * LPQ / QBLK), dim3(QBLK), 0, stream>>>(
        (const float2*)feat, nverts, cnt, spillCnt, buckets, spill,
        (float2*)outp);
}